// Round 1
// baseline (598.325 us; speedup 1.0000x reference)
//
#include <hip/hip_runtime.h>

// out = x * exp(-sigma^2/2 + sigma*eps), sigma = 0.5
// N = 8*4096*2048 = 67108864 fp32; memory-bound: 512 MiB read + 256 MiB write.
// L3 (256 MiB) serves ~half the reads; HBM sees ~512 MiB/dispatch.
//
// R1: persistent grid-stride kernel, 2048 blocks (8/CU), UNROLL=4 batched
// grid-strided loads per iteration. Rationale: previous flat launch (65536
// one-shot WGs) had only 2 KB outstanding per wave and paid 32 generations of
// workgroup churn per CU; this keeps all waves resident and 8 KB in flight
// per wave before the first waitcnt.

#define SIGMA  0.5f
#define BIAS  (-0.125f)   // -sigma^2/2

constexpr int BLOCK  = 256;
constexpr int UNROLL = 4;
constexpr int MAX_BLOCKS = 2048;   // 256 CU × 8 blocks/CU (32 waves/CU cap)

__global__ __launch_bounds__(BLOCK) void sdo_kernel(const float4* __restrict__ x,
                                                    const float4* __restrict__ eps,
                                                    float4* __restrict__ out,
                                                    int n4) {
    const int nthreads = gridDim.x * BLOCK;
    const int tid      = blockIdx.x * BLOCK + threadIdx.x;
    const int per_round = nthreads * UNROLL;
    const int nfull     = (n4 / per_round) * per_round;  // rounds with no bounds checks

    int i = tid;
    for (; i < nfull; i += per_round) {
        float4 xv[UNROLL], ev[UNROLL];
        // Batch all 8 loads first — 8 KB in flight per wave, each load
        // instruction fully coalesced (lanes contiguous, chunks grid-strided).
#pragma unroll
        for (int u = 0; u < UNROLL; ++u) {
            xv[u] = x[i + u * nthreads];
            ev[u] = eps[i + u * nthreads];
        }
#pragma unroll
        for (int u = 0; u < UNROLL; ++u) {
            float4 ov;
            ov.x = xv[u].x * __expf(fmaf(SIGMA, ev[u].x, BIAS));
            ov.y = xv[u].y * __expf(fmaf(SIGMA, ev[u].y, BIAS));
            ov.z = xv[u].z * __expf(fmaf(SIGMA, ev[u].z, BIAS));
            ov.w = xv[u].w * __expf(fmaf(SIGMA, ev[u].w, BIAS));
            out[i + u * nthreads] = ov;
        }
    }
    // Tail (empty for n4 = 2^24 with grid = 2048, but keep it general).
    for (; i < n4; i += nthreads) {
        float4 xv = x[i];
        float4 ev = eps[i];
        float4 ov;
        ov.x = xv.x * __expf(fmaf(SIGMA, ev.x, BIAS));
        ov.y = xv.y * __expf(fmaf(SIGMA, ev.y, BIAS));
        ov.z = xv.z * __expf(fmaf(SIGMA, ev.z, BIAS));
        ov.w = xv.w * __expf(fmaf(SIGMA, ev.w, BIAS));
        out[i] = ov;
    }
}

extern "C" void kernel_launch(void* const* d_in, const int* in_sizes, int n_in,
                              void* d_out, int out_size, void* d_ws, size_t ws_size,
                              hipStream_t stream) {
    const float4* x   = (const float4*)d_in[0];
    const float4* eps = (const float4*)d_in[1];
    float4* out       = (float4*)d_out;
    int n  = in_sizes[0];        // 67108864
    int n4 = n >> 2;             // 16777216 (n % 4 == 0)
    int grid = (n4 + BLOCK * UNROLL - 1) / (BLOCK * UNROLL);
    if (grid > MAX_BLOCKS) grid = MAX_BLOCKS;   // 2048 for this shape
    sdo_kernel<<<grid, BLOCK, 0, stream>>>(x, eps, out, n4);
}